// Round 14
// baseline (23.380 us; speedup 1.0000x reference)
//
#include <hip/hip_runtime.h>
#include <math.h>

#define BB 64
#define NN 2048
#define DD 128
#define KD 16
#define NORMF 0.25f
#define CHUNK 32
#define PSTRIDE 260                 // per-block partial: 2*DD + 2 + pad
#define LOG2E 1.4426950408889634f

// wave-local LDS fence: DS ops within a wave are in-order; drain before cross-lane reads.
__device__ __forceinline__ void wave_lds_fence() {
    asm volatile("s_waitcnt lgkmcnt(0)" ::: "memory");
    __builtin_amdgcn_wave_barrier();
}

// ---------------- main: UNCONDITIONAL streaming over h, partials -> ws ----------------
// R14 experiment: h-row loads issued FIRST with no adj/ballot dependency (removes one
// serial HBM round trip per wave). adj only feeds the es-zeroing, loaded in parallel.
// VGPR note: hv0+hv1 = 128 VGPRs of prefetch at the 256-VGPR cliff under (256,2).
// Do NOT duplicate code paths or raise min-waves (R10/R11 spill regressions).
template <int P>
__global__ __launch_bounds__(256, 2)
void attn_main(const float* __restrict__ h,
               const float* __restrict__ adj,
               const int*   __restrict__ phone,
               const float* __restrict__ Wq_bf, const float* __restrict__ Wk_bf,
               const float* __restrict__ Wq_af, const float* __restrict__ Wk_af,
               float* __restrict__ ws)
{
    constexpr int K = 16 / P;          // chunks per wave (2 on the main path)
    const int tid  = threadIdx.x;
    const int wid  = tid >> 6;
    const int lane = tid & 63;
    const int half = lane >> 5;
    const int l    = lane & 31;
    const int dbase = 4 * l;

    // XCD swizzle: all P blocks of a batch on one XCD
    const int xcd  = blockIdx.x & 7;
    const int slot = blockIdx.x >> 3;
    const int b    = xcd + 8 * (slot / P);
    const int bip  = slot % P;

    __shared__ float hp[DD];
    __shared__ float qpart[32][8];
    __shared__ float q[2][KD];
    __shared__ float w_s[2][DD];
    __shared__ float part[4][CHUNK][33];
    __shared__ float ea_s[4][CHUNK];
    __shared__ float red_h[4][2][DD];
    __shared__ float red_s[4][2];

    const float* hb  = h + (size_t)b * NN * DD;
    const int chbase = (bip * 4 + wid) * K;

    // ---- (1) h-row loads FIRST: no dependency on anything but b (phone not needed)
    auto load_chunk = [&](float4* hv, int n0) {
        #pragma unroll
        for (int t = 0; t < 16; ++t) {
            const int r = 2 * t + half;
            hv[t] = *(const float4*)(hb + (size_t)(n0 + r) * DD + dbase);
        }
    };

    float4 hv0[16], hv1[16];
    load_chunk(hv0, (chbase + 0) * CHUNK);
    if (K > 1) load_chunk(hv1, (chbase + 1) * CHUNK);

    // ---- (2) phone, adj, h_phone (in flight alongside the h stream)
    const int ph = phone[b];
    const float* adjrow = adj + ((size_t)b * NN + ph) * NN;
    float adjv[K];
    #pragma unroll
    for (int c = 0; c < K; ++c) adjv[c] = adjrow[(chbase + c) * CHUNK + l];

    if (tid < DD) hp[tid] = hb[(size_t)ph * DD + tid];

    // ---- (3) weight slices into registers
    const int pair = tid >> 3, sub = tid & 7;       // q-GEMV role: (br,k) x 8-way d-split
    const int brq = pair >> 4, kq = pair & 15;
    const float* Wq = brq ? Wq_af : Wq_bf;
    float wqr[16];
    #pragma unroll
    for (int i = 0; i < 16; ++i) wqr[i] = Wq[(sub * 16 + i) * KD + kq];

    const int brw = tid >> 7, dw = tid & 127;       // w-GEMV role: (br,d)
    const float* Wk = brw ? Wk_af : Wk_bf;
    float wkr[KD];
    #pragma unroll
    for (int k = 0; k < KD; ++k) wkr[k] = Wk[dw * KD + k];

    // ---- (4) prologue GEMV chain (pure reg/LDS compute; HBM traffic in flight)
    __syncthreads();                                 // hp ready
    {
        float acc = 0.f;
        #pragma unroll
        for (int i = 0; i < 16; ++i) acc += hp[sub * 16 + i] * wqr[i];
        qpart[pair][sub] = acc;
    }
    __syncthreads();
    if (tid < 32) {
        float acc = 0.f;
        #pragma unroll
        for (int i = 0; i < 8; ++i) acc += qpart[tid][i];
        q[tid >> 4][tid & 15] = acc;
    }
    __syncthreads();
    {
        float acc = 0.f;
        #pragma unroll
        for (int k = 0; k < KD; ++k) acc += wkr[k] * q[brw][k];
        w_s[brw][dw] = NORMF * acc;
    }
    __syncthreads();

    const float4 wbf = *(const float4*)(&w_s[0][dbase]);
    const float4 waf = *(const float4*)(&w_s[1][dbase]);

    float sbf = 0.f, saf = 0.f;
    float hgbf[4] = {0, 0, 0, 0}, hgaf[4] = {0, 0, 0, 0};

    // e = exp(10*tanh(p) - 10) = exp2(-20*log2e / (exp2(2p*log2e) + 1))   (exact identity)
    auto softexp = [](float p) {
        const float t = __builtin_amdgcn_exp2f(2.f * LOG2E * p);
        return __builtin_amdgcn_exp2f(-20.f * LOG2E * __builtin_amdgcn_rcpf(t + 1.f));
    };

    auto compute_chunk = [&](int n0, const float4* hv, float adjc) {
        // phase A: per-lane partial dots -> LDS transpose (wave-private)
        #pragma unroll
        for (int t = 0; t < 16; ++t) {
            const int r = 2 * t + half;
            const float4 w = ((n0 + r) >= ph) ? waf : wbf;
            part[wid][r][l] = hv[t].x * w.x + hv[t].y * w.y + hv[t].z * w.z + hv[t].w * w.w;
        }
        wave_lds_fence();

        // phase B: one row per lane (halves duplicate rows 0..31)
        float a0 = 0.f, a1 = 0.f, a2 = 0.f, a3 = 0.f;
        #pragma unroll
        for (int j = 0; j < 32; j += 4) {
            a0 += part[wid][l][j];
            a1 += part[wid][l][j + 1];
            a2 += part[wid][l][j + 2];
            a3 += part[wid][l][j + 3];
        }
        const float p = (a0 + a1) + (a2 + a3);
        const float e = softexp(p);
        const float es = (adjc != 0.f) ? e : 0.f;    // masked rows contribute exactly 0
        const float ea = es * adjc;
        const bool rowaf = (n0 + l) >= ph;
        sbf += rowaf ? 0.f : es;
        saf += rowaf ? es : 0.f;
        if (lane < 32) ea_s[wid][l] = ea;
        wave_lds_fence();

        // phase C: weighted accumulation from registers
        #pragma unroll
        for (int t = 0; t < 16; ++t) {
            const int r = 2 * t + half;
            const float ear = ea_s[wid][r];               // broadcast read
            const bool af = (n0 + r) >= ph;
            const float eb = af ? 0.f : ear;
            const float ef = af ? ear : 0.f;
            hgbf[0] += eb * hv[t].x; hgbf[1] += eb * hv[t].y;
            hgbf[2] += eb * hv[t].z; hgbf[3] += eb * hv[t].w;
            hgaf[0] += ef * hv[t].x; hgaf[1] += ef * hv[t].y;
            hgaf[2] += ef * hv[t].z; hgaf[3] += ef * hv[t].w;
        }
    };

    // ---- (5) compute the preloaded pair, then remaining pairs (K>2 fallback only)
    compute_chunk((chbase + 0) * CHUNK, hv0, adjv[0]);
    if (K > 1) compute_chunk((chbase + 1) * CHUNK, hv1, adjv[1]);

    #pragma unroll
    for (int cc = 2; cc < K; cc += 2) {
        load_chunk(hv0, (chbase + cc) * CHUNK);
        if (cc + 1 < K) load_chunk(hv1, (chbase + cc + 1) * CHUNK);
        compute_chunk((chbase + cc) * CHUNK, hv0, adjv[cc]);
        if (cc + 1 < K) compute_chunk((chbase + cc + 1) * CHUNK, hv1, adjv[cc + 1]);
    }

    // ---- per-wave reductions
    #pragma unroll
    for (int m = 1; m <= 16; m <<= 1) {
        sbf += __shfl_xor(sbf, m, 64);
        saf += __shfl_xor(saf, m, 64);
    }
    #pragma unroll
    for (int i = 0; i < 4; ++i) {
        hgbf[i] += __shfl_xor(hgbf[i], 32, 64);   // combine halves (same d-range)
        hgaf[i] += __shfl_xor(hgaf[i], 32, 64);
    }
    if (lane < 32) {
        #pragma unroll
        for (int i = 0; i < 4; ++i) {
            red_h[wid][0][dbase + i] = hgbf[i];
            red_h[wid][1][dbase + i] = hgaf[i];
        }
    }
    if (lane == 0) { red_s[wid][0] = sbf; red_s[wid][1] = saf; }
    __syncthreads();   // the only cross-wave exchange

    {   // block partial -> ws (coalesced, no atomics, no fences)
        const int br = tid >> 7, d = tid & 127;
        float* op = ws + (size_t)(b * P + bip) * PSTRIDE;
        op[br * DD + d] = red_h[0][br][d] + red_h[1][br][d] + red_h[2][br][d] + red_h[3][br][d];
        if (tid < 2)
            op[2 * DD + tid] = red_s[0][tid] + red_s[1][tid] + red_s[2][tid] + red_s[3][tid];
    }
}

// ---------------- finalize: reduce P partials, head = hagg@Wv, out = (head@Wo)/s ----
template <int P>
__global__ __launch_bounds__(256)
void finalize_kernel(const float* __restrict__ Wv_bf, const float* __restrict__ Wo_bf,
                     const float* __restrict__ Wv_af, const float* __restrict__ Wo_af,
                     const float* __restrict__ ws, float* __restrict__ out)
{
    const int b = blockIdx.x;
    const int tid = threadIdx.x;
    __shared__ float hs[2][DD];
    __shared__ float ssum[2];
    __shared__ float hpart[32][8];
    __shared__ float head[2][KD];

    // issue ALL independent loads up front
    const int pair = tid >> 3, sub = tid & 7;
    const int brv = pair >> 4, kv = pair & 15;
    const float* Wv = brv ? Wv_af : Wv_bf;
    float wvr[16];
    #pragma unroll
    for (int i = 0; i < 16; ++i) wvr[i] = Wv[(sub * 16 + i) * KD + kv];

    const int br2 = tid >> 7, j = tid & 127;
    const float* Wo = br2 ? Wo_af : Wo_bf;
    float wor[KD];
    #pragma unroll
    for (int k = 0; k < KD; ++k) wor[k] = Wo[k * DD + j];

    const float* base = ws + (size_t)b * P * PSTRIDE;
    {
        float acc = 0.f;
        #pragma unroll
        for (int p = 0; p < P; ++p) acc += base[(size_t)p * PSTRIDE + br2 * DD + j];
        hs[br2][j] = acc;
    }
    if (tid < 2) {
        float acc = 0.f;
        #pragma unroll
        for (int p = 0; p < P; ++p) acc += base[(size_t)p * PSTRIDE + 2 * DD + tid];
        ssum[tid] = acc;
    }
    __syncthreads();

    {
        float acc = 0.f;
        #pragma unroll
        for (int i = 0; i < 16; ++i) acc += hs[brv][sub * 16 + i] * wvr[i];
        hpart[pair][sub] = acc;
    }
    __syncthreads();
    if (tid < 32) {
        float acc = 0.f;
        #pragma unroll
        for (int i = 0; i < 8; ++i) acc += hpart[tid][i];
        head[tid >> 4][tid & 15] = acc;
    }
    __syncthreads();

    {
        const float s = ssum[br2];
        const float inv = (s > 0.f) ? 1.f / s : 0.f;
        float acc = 0.f;
        #pragma unroll
        for (int k = 0; k < KD; ++k) acc += head[br2][k] * wor[k];
        out[br2 * BB * DD + b * DD + j] = acc * inv;
    }
}

extern "C" void kernel_launch(void* const* d_in, const int* in_sizes, int n_in,
                              void* d_out, int out_size, void* d_ws, size_t ws_size,
                              hipStream_t stream) {
    const float* h     = (const float*)d_in[0];
    const float* adj   = (const float*)d_in[1];
    const int*   phone = (const int*)d_in[2];
    const float* Wq_bf = (const float*)d_in[3];
    const float* Wk_bf = (const float*)d_in[4];
    const float* Wv_bf = (const float*)d_in[5];
    const float* Wo_bf = (const float*)d_in[6];
    const float* Wq_af = (const float*)d_in[7];
    const float* Wk_af = (const float*)d_in[8];
    const float* Wv_af = (const float*)d_in[9];
    const float* Wo_af = (const float*)d_in[10];

    float* out = (float*)d_out;
    float* ws  = (float*)d_ws;

    // largest compile-time P (<=8) whose partial region fits ws
    int P = 8;
    while (P > 1 && (size_t)BB * P * PSTRIDE * sizeof(float) > ws_size) P >>= 1;

    switch (P) {
    case 8:
        attn_main<8><<<BB * 8, 256, 0, stream>>>(h, adj, phone, Wq_bf, Wk_bf, Wq_af, Wk_af, ws);
        finalize_kernel<8><<<BB, 256, 0, stream>>>(Wv_bf, Wo_bf, Wv_af, Wo_af, ws, out);
        break;
    case 4:
        attn_main<4><<<BB * 4, 256, 0, stream>>>(h, adj, phone, Wq_bf, Wk_bf, Wq_af, Wk_af, ws);
        finalize_kernel<4><<<BB, 256, 0, stream>>>(Wv_bf, Wo_bf, Wv_af, Wo_af, ws, out);
        break;
    case 2:
        attn_main<2><<<BB * 2, 256, 0, stream>>>(h, adj, phone, Wq_bf, Wk_bf, Wq_af, Wk_af, ws);
        finalize_kernel<2><<<BB, 256, 0, stream>>>(Wv_bf, Wo_bf, Wv_af, Wo_af, ws, out);
        break;
    default:
        attn_main<1><<<BB, 256, 0, stream>>>(h, adj, phone, Wq_bf, Wk_bf, Wq_af, Wk_af, ws);
        finalize_kernel<1><<<BB, 256, 0, stream>>>(Wv_bf, Wo_bf, Wv_af, Wo_af, ws, out);
        break;
    }
}

// Round 15
// 17.217 us; speedup vs baseline: 1.3579x; 1.3579x over previous
//
#include <hip/hip_runtime.h>
#include <math.h>

#define BB 64
#define NN 2048
#define DD 128
#define KD 16
#define NORMF 0.25f
#define CHUNK 32
#define PSTRIDE 260                 // per-block partial: 2*DD + 2 + pad
#define LOG2E 1.4426950408889634f

// wave-local LDS fence: DS ops within a wave are in-order; drain before cross-lane reads.
__device__ __forceinline__ void wave_lds_fence() {
    asm volatile("s_waitcnt lgkmcnt(0)" ::: "memory");
    __builtin_amdgcn_wave_barrier();
}

// soft block barrier: drains own LDS ops then raw s_barrier — does NOT drain vmcnt,
// so global loads issued before it stay in flight (unlike __syncthreads, which emits
// s_waitcnt vmcnt(0) and kills the h-prefetch overlap).
__device__ __forceinline__ void soft_barrier() {
    asm volatile("s_waitcnt lgkmcnt(0)" ::: "memory");
    __builtin_amdgcn_s_barrier();
}

// ---------------- main: prologue + masked streaming over h, partials -> ws ----------------
// Issue order: adj -> h_phone -> weight regs -> ballot -> ALL h-row loads -> prologue GEMVs.
// Prologue uses soft_barrier so the 32 h-row loads remain outstanding across it.
// VGPR note: hv0+hv1 = 128 VGPRs of prefetch at the 256-VGPR cliff under (256,2).
// Do NOT duplicate code paths or raise min-waves (R10/R11 spill regressions).
template <int P>
__global__ __launch_bounds__(256, 2)
void attn_main(const float* __restrict__ h,
               const float* __restrict__ adj,
               const int*   __restrict__ phone,
               const float* __restrict__ Wq_bf, const float* __restrict__ Wk_bf,
               const float* __restrict__ Wq_af, const float* __restrict__ Wk_af,
               float* __restrict__ ws)
{
    constexpr int K = 16 / P;          // chunks per wave (2 on the main path)
    const int tid  = threadIdx.x;
    const int wid  = tid >> 6;
    const int lane = tid & 63;
    const int half = lane >> 5;
    const int l    = lane & 31;
    const int dbase = 4 * l;

    // XCD swizzle: all P blocks of a batch on one XCD
    const int xcd  = blockIdx.x & 7;
    const int slot = blockIdx.x >> 3;
    const int b    = xcd + 8 * (slot / P);
    const int bip  = slot % P;
    const int ph   = phone[b];

    __shared__ float hp[DD];
    __shared__ float qpart[32][8];
    __shared__ float q[2][KD];
    __shared__ float w_s[2][DD];
    __shared__ float part[4][CHUNK][33];
    __shared__ float ea_s[4][CHUNK];
    __shared__ float red_h[4][2][DD];
    __shared__ float red_s[4][2];

    const float* hb     = h + (size_t)b * NN * DD;
    const float* adjrow = adj + ((size_t)b * NN + ph) * NN;
    const int chbase    = (bip * 4 + wid) * K;

    // ---- (1) adjacency loads for all K chunks
    float adjv[K];
    #pragma unroll
    for (int c = 0; c < K; ++c) adjv[c] = adjrow[(chbase + c) * CHUNK + l];

    // ---- (2) h_phone
    if (tid < DD) hp[tid] = hb[(size_t)ph * DD + tid];

    // ---- (3) weight slices into registers (keeps global loads out of the GEMV chains)
    const int pair = tid >> 3, sub = tid & 7;       // q-GEMV role: (br,k) x 8-way d-split
    const int brq = pair >> 4, kq = pair & 15;
    const float* Wq = brq ? Wq_af : Wq_bf;
    float wqr[16];
    #pragma unroll
    for (int i = 0; i < 16; ++i) wqr[i] = Wq[(sub * 16 + i) * KD + kq];

    const int brw = tid >> 7, dw = tid & 127;       // w-GEMV role: (br,d)
    const float* Wk = brw ? Wk_af : Wk_bf;
    float wkr[KD];
    #pragma unroll
    for (int k = 0; k < KD; ++k) wkr[k] = Wk[dw * KD + k];

    // ---- (4) ballots + issue ALL h-row loads for the first pair (stay in flight
    //          across the soft-barrier prologue below)
    auto load_chunk = [&](float4* hv, unsigned long long mask, int n0) {
        #pragma unroll
        for (int t = 0; t < 16; ++t) {
            const int r = 2 * t + half;
            hv[t] = make_float4(0.f, 0.f, 0.f, 0.f);
            if ((mask >> r) & 1ull)      // wave-uniform branch
                hv[t] = *(const float4*)(hb + (size_t)(n0 + r) * DD + dbase);
        }
    };

    float4 hv0[16], hv1[16];
    {
        const unsigned long long m0 = __ballot(adjv[0] != 0.f);
        load_chunk(hv0, m0, (chbase + 0) * CHUNK);
        if (K > 1) {
            const unsigned long long m1 = __ballot(adjv[1] != 0.f);
            load_chunk(hv1, m1, (chbase + 1) * CHUNK);
        }
    }

    // ---- (5) prologue GEMV chain under soft barriers (h HBM traffic stays in flight)
    soft_barrier();                                  // hp ready (lgkm-drained, no vmcnt(0))
    {
        float acc = 0.f;
        #pragma unroll
        for (int i = 0; i < 16; ++i) acc += hp[sub * 16 + i] * wqr[i];
        qpart[pair][sub] = acc;
    }
    soft_barrier();
    if (tid < 32) {
        float acc = 0.f;
        #pragma unroll
        for (int i = 0; i < 8; ++i) acc += qpart[tid][i];
        q[tid >> 4][tid & 15] = acc;
    }
    soft_barrier();
    {
        float acc = 0.f;
        #pragma unroll
        for (int k = 0; k < KD; ++k) acc += wkr[k] * q[brw][k];
        w_s[brw][dw] = NORMF * acc;
    }
    soft_barrier();

    const float4 wbf = *(const float4*)(&w_s[0][dbase]);
    const float4 waf = *(const float4*)(&w_s[1][dbase]);

    float sbf = 0.f, saf = 0.f;
    float hgbf[4] = {0, 0, 0, 0}, hgaf[4] = {0, 0, 0, 0};

    // e = exp(10*tanh(p) - 10) = exp2(-20*log2e / (exp2(2p*log2e) + 1))   (exact identity)
    auto softexp = [](float p) {
        const float t = __builtin_amdgcn_exp2f(2.f * LOG2E * p);
        return __builtin_amdgcn_exp2f(-20.f * LOG2E * __builtin_amdgcn_rcpf(t + 1.f));
    };

    auto compute_chunk = [&](int n0, const float4* hv, float adjc) {
        // phase A: per-lane partial dots -> LDS transpose (wave-private)
        #pragma unroll
        for (int t = 0; t < 16; ++t) {
            const int r = 2 * t + half;
            const float4 w = ((n0 + r) >= ph) ? waf : wbf;
            part[wid][r][l] = hv[t].x * w.x + hv[t].y * w.y + hv[t].z * w.z + hv[t].w * w.w;
        }
        wave_lds_fence();

        // phase B: one row per lane (halves duplicate rows 0..31)
        float a0 = 0.f, a1 = 0.f, a2 = 0.f, a3 = 0.f;
        #pragma unroll
        for (int j = 0; j < 32; j += 4) {
            a0 += part[wid][l][j];
            a1 += part[wid][l][j + 1];
            a2 += part[wid][l][j + 2];
            a3 += part[wid][l][j + 3];
        }
        const float p = (a0 + a1) + (a2 + a3);
        const float e = softexp(p);
        const float es = (adjc != 0.f) ? e : 0.f;
        const float ea = es * adjc;
        const bool rowaf = (n0 + l) >= ph;
        sbf += rowaf ? 0.f : es;
        saf += rowaf ? es : 0.f;
        if (lane < 32) ea_s[wid][l] = ea;
        wave_lds_fence();

        // phase C: weighted accumulation from registers
        #pragma unroll
        for (int t = 0; t < 16; ++t) {
            const int r = 2 * t + half;
            const float ear = ea_s[wid][r];               // broadcast read
            const bool af = (n0 + r) >= ph;
            const float eb = af ? 0.f : ear;
            const float ef = af ? ear : 0.f;
            hgbf[0] += eb * hv[t].x; hgbf[1] += eb * hv[t].y;
            hgbf[2] += eb * hv[t].z; hgbf[3] += eb * hv[t].w;
            hgaf[0] += ef * hv[t].x; hgaf[1] += ef * hv[t].y;
            hgaf[2] += ef * hv[t].z; hgaf[3] += ef * hv[t].w;
        }
    };

    // ---- (6) compute the preloaded pair, then remaining pairs (K>2 fallback only)
    compute_chunk((chbase + 0) * CHUNK, hv0, adjv[0]);
    if (K > 1) compute_chunk((chbase + 1) * CHUNK, hv1, adjv[1]);

    #pragma unroll
    for (int cc = 2; cc < K; cc += 2) {
        const unsigned long long m0 = __ballot(adjv[cc] != 0.f);
        load_chunk(hv0, m0, (chbase + cc) * CHUNK);
        if (cc + 1 < K) {
            const unsigned long long m1 = __ballot(adjv[cc + 1] != 0.f);
            load_chunk(hv1, m1, (chbase + cc + 1) * CHUNK);
        }
        compute_chunk((chbase + cc) * CHUNK, hv0, adjv[cc]);
        if (cc + 1 < K) compute_chunk((chbase + cc + 1) * CHUNK, hv1, adjv[cc + 1]);
    }

    // ---- per-wave reductions
    #pragma unroll
    for (int m = 1; m <= 16; m <<= 1) {
        sbf += __shfl_xor(sbf, m, 64);
        saf += __shfl_xor(saf, m, 64);
    }
    #pragma unroll
    for (int i = 0; i < 4; ++i) {
        hgbf[i] += __shfl_xor(hgbf[i], 32, 64);   // combine halves (same d-range)
        hgaf[i] += __shfl_xor(hgaf[i], 32, 64);
    }
    if (lane < 32) {
        #pragma unroll
        for (int i = 0; i < 4; ++i) {
            red_h[wid][0][dbase + i] = hgbf[i];
            red_h[wid][1][dbase + i] = hgaf[i];
        }
    }
    if (lane == 0) { red_s[wid][0] = sbf; red_s[wid][1] = saf; }
    __syncthreads();   // real barrier: cross-wave exchange (all loads consumed by now)

    {   // block partial -> ws (coalesced, no atomics, no fences)
        const int br = tid >> 7, d = tid & 127;
        float* op = ws + (size_t)(b * P + bip) * PSTRIDE;
        op[br * DD + d] = red_h[0][br][d] + red_h[1][br][d] + red_h[2][br][d] + red_h[3][br][d];
        if (tid < 2)
            op[2 * DD + tid] = red_s[0][tid] + red_s[1][tid] + red_s[2][tid] + red_s[3][tid];
    }
}

// ---------------- finalize: reduce P partials, head = hagg@Wv, out = (head@Wo)/s ----
template <int P>
__global__ __launch_bounds__(256)
void finalize_kernel(const float* __restrict__ Wv_bf, const float* __restrict__ Wo_bf,
                     const float* __restrict__ Wv_af, const float* __restrict__ Wo_af,
                     const float* __restrict__ ws, float* __restrict__ out)
{
    const int b = blockIdx.x;
    const int tid = threadIdx.x;
    __shared__ float hs[2][DD];
    __shared__ float ssum[2];
    __shared__ float hpart[32][8];
    __shared__ float head[2][KD];

    // issue ALL independent loads up front
    const int pair = tid >> 3, sub = tid & 7;
    const int brv = pair >> 4, kv = pair & 15;
    const float* Wv = brv ? Wv_af : Wv_bf;
    float wvr[16];
    #pragma unroll
    for (int i = 0; i < 16; ++i) wvr[i] = Wv[(sub * 16 + i) * KD + kv];

    const int br2 = tid >> 7, j = tid & 127;
    const float* Wo = br2 ? Wo_af : Wo_bf;
    float wor[KD];
    #pragma unroll
    for (int k = 0; k < KD; ++k) wor[k] = Wo[k * DD + j];

    const float* base = ws + (size_t)b * P * PSTRIDE;
    {
        float acc = 0.f;
        #pragma unroll
        for (int p = 0; p < P; ++p) acc += base[(size_t)p * PSTRIDE + br2 * DD + j];
        hs[br2][j] = acc;
    }
    if (tid < 2) {
        float acc = 0.f;
        #pragma unroll
        for (int p = 0; p < P; ++p) acc += base[(size_t)p * PSTRIDE + 2 * DD + tid];
        ssum[tid] = acc;
    }
    __syncthreads();

    {
        float acc = 0.f;
        #pragma unroll
        for (int i = 0; i < 16; ++i) acc += hs[brv][sub * 16 + i] * wvr[i];
        hpart[pair][sub] = acc;
    }
    __syncthreads();
    if (tid < 32) {
        float acc = 0.f;
        #pragma unroll
        for (int i = 0; i < 8; ++i) acc += hpart[tid][i];
        head[tid >> 4][tid & 15] = acc;
    }
    __syncthreads();

    {
        const float s = ssum[br2];
        const float inv = (s > 0.f) ? 1.f / s : 0.f;
        float acc = 0.f;
        #pragma unroll
        for (int k = 0; k < KD; ++k) acc += head[br2][k] * wor[k];
        out[br2 * BB * DD + b * DD + j] = acc * inv;
    }
}

extern "C" void kernel_launch(void* const* d_in, const int* in_sizes, int n_in,
                              void* d_out, int out_size, void* d_ws, size_t ws_size,
                              hipStream_t stream) {
    const float* h     = (const float*)d_in[0];
    const float* adj   = (const float*)d_in[1];
    const int*   phone = (const int*)d_in[2];
    const float* Wq_bf = (const float*)d_in[3];
    const float* Wk_bf = (const float*)d_in[4];
    const float* Wv_bf = (const float*)d_in[5];
    const float* Wo_bf = (const float*)d_in[6];
    const float* Wq_af = (const float*)d_in[7];
    const float* Wk_af = (const float*)d_in[8];
    const float* Wv_af = (const float*)d_in[9];
    const float* Wo_af = (const float*)d_in[10];

    float* out = (float*)d_out;
    float* ws  = (float*)d_ws;

    // largest compile-time P (<=8) whose partial region fits ws
    int P = 8;
    while (P > 1 && (size_t)BB * P * PSTRIDE * sizeof(float) > ws_size) P >>= 1;

    switch (P) {
    case 8:
        attn_main<8><<<BB * 8, 256, 0, stream>>>(h, adj, phone, Wq_bf, Wk_bf, Wq_af, Wk_af, ws);
        finalize_kernel<8><<<BB, 256, 0, stream>>>(Wv_bf, Wo_bf, Wv_af, Wo_af, ws, out);
        break;
    case 4:
        attn_main<4><<<BB * 4, 256, 0, stream>>>(h, adj, phone, Wq_bf, Wk_bf, Wq_af, Wk_af, ws);
        finalize_kernel<4><<<BB, 256, 0, stream>>>(Wv_bf, Wo_bf, Wv_af, Wo_af, ws, out);
        break;
    case 2:
        attn_main<2><<<BB * 2, 256, 0, stream>>>(h, adj, phone, Wq_bf, Wk_bf, Wq_af, Wk_af, ws);
        finalize_kernel<2><<<BB, 256, 0, stream>>>(Wv_bf, Wo_bf, Wv_af, Wo_af, ws, out);
        break;
    default:
        attn_main<1><<<BB, 256, 0, stream>>>(h, adj, phone, Wq_bf, Wk_bf, Wq_af, Wk_af, ws);
        finalize_kernel<1><<<BB, 256, 0, stream>>>(Wv_bf, Wo_bf, Wv_af, Wo_af, ws, out);
        break;
    }
}